// Round 6
// baseline (99.106 us; speedup 1.0000x reference)
//
#include <hip/hip_runtime.h>
#include <math.h>

#define TPB 256
#define IB 64            // i-blocks; span = n/IB = 128 (must be 2*64)
#define EPSF 1e-15f

// Fused prep + O(n^2) pair kernel, LDS-FREE inner loop.
// i-span data lives in per-wave REGISTERS; broadcast via v_readlane (no LDS
// pipe contention — LDS is per-CU shared by 4 SIMDs and was the R4 limiter).
// Rs = (g1+log y)/(h*sqrt(2 ln 2)) so exp(-0.5*((R_i-R_j)/h)^2) = exp2(-dr^2).
// V_i = (d_i ? -L_i : +L_i): sign bit carries d_i (L_i = exp(g2-g1) > 0).
// A_j = sum_i d_i*e;  L*Phi = 0.5*L + copysign(L,dr)*(0.5-u),
// u = upper-tail Q via A&S 7.1.25 3-term erfc (|eps|<=2.5e-5), reusing the
// SAME exp2. 0.5*sum_span(L) folded once (spans partition i).
__global__ __launch_bounds__(TPB, 8) void pair_kernel(
    const float* __restrict__ m_z, const float* __restrict__ y,
    const float* __restrict__ delta, float2* __restrict__ P,
    float* __restrict__ out, float inv_hk, int n, int span) {
    const int tid = threadIdx.x;
    const int lane = tid & 63;
    const int j = blockIdx.x * TPB + tid;
    const float2* __restrict__ mz2 = (const float2*)m_z;

    if (j == 0 && blockIdx.y == 0) out[0] = 0.0f;  // harness poisons d_out

    const float2 gj = mz2[j];
    const float Rj = (gj.x + __logf(y[j])) * inv_hk;

    // Per-wave register copy of this block's i-span (span = 2*64).
    const int ibase = blockIdx.y * span;
    float vR[2], vV[2];
    float lsum = 0.0f;
#pragma unroll
    for (int r = 0; r < 2; ++r) {
        const int i = ibase + r * 64 + lane;
        const float2 g = mz2[i];
        vR[r] = (g.x + __logf(y[i])) * inv_hk;
        const float L = __expf(g.y - g.x);
        vV[r] = (delta[i] != 0.0f) ? -L : L;   // sign bit carries d_i
        lsum += L;
    }
    // one-time wave reduce: every lane gets sum_span L
    for (int o = 32; o > 0; o >>= 1) lsum += __shfl_xor(lsum, o, 64);

    float accA = 0.0f;
    float accB = 0.5f * lsum;
#pragma unroll
    for (int r = 0; r < 2; ++r) {
#pragma unroll 16
        for (int k = 0; k < 64; ++k) {
            // SGPR broadcasts — zero LDS traffic
            const float sR = __int_as_float(
                __builtin_amdgcn_readlane(__float_as_int(vR[r]), k));
            const float sV = __int_as_float(
                __builtin_amdgcn_readlane(__float_as_int(vV[r]), k));
            const float sd = (sV < 0.0f) ? 1.0f : 0.0f;  // scalar pipe (uniform)
            const float sL = fabsf(sV);                  // scalar pipe (uniform)
            const float dr = sR - Rj;
            const float q = dr * dr;
            const float e = __builtin_amdgcn_exp2f(-q);  // exp(-dr_true^2/2)
            const float t = __builtin_amdgcn_rcpf(fmaf(0.3916993f, fabsf(dr), 1.0f));
            const float u = t * fmaf(t, fmaf(t, 0.3739278f, -0.0479399f),
                                     0.1740121f) * e;
            accA = fmaf(sd, e, accA);
            accB = fmaf(copysignf(sL, dr), 0.5f - u, accB);
        }
    }
    P[(size_t)blockIdx.y * n + j] = make_float2(accA, accB);
}

// out = (1/n) * sum_j d_j * (R_j - g2_j - log(c1*A_j + eps) + log(invn*B_j + eps))
__global__ __launch_bounds__(TPB) void finalize_kernel(
    const float2* __restrict__ P, const float* __restrict__ m_z,
    const float* __restrict__ y, const float* __restrict__ delta,
    float* __restrict__ out, float c1, float invn, int n) {
    const int j = blockIdx.x * TPB + threadIdx.x;
    float sa = 0.0f, sb = 0.0f;
    for (int b = 0; b < IB; ++b) {               // coalesced float2 reads
        const float2 v = P[(size_t)b * n + j];
        sa += v.x;
        sb += v.y;
    }
    const float d = delta[j];
    const float R = m_z[2 * j] + __logf(y[j]);
    float term = d * (R - m_z[2 * j + 1] - __logf(fmaf(c1, sa, EPSF))
                                         + __logf(fmaf(invn, sb, EPSF)));
    for (int o = 32; o > 0; o >>= 1) term += __shfl_down(term, o, 64);
    __shared__ float wsum[TPB / 64];
    if ((threadIdx.x & 63) == 0) wsum[threadIdx.x >> 6] = term;
    __syncthreads();
    if (threadIdx.x == 0) {
        float ssum = 0.0f;
        for (int w = 0; w < TPB / 64; ++w) ssum += wsum[w];
        atomicAdd(out, ssum * invn);
    }
}

extern "C" void kernel_launch(void* const* d_in, const int* in_sizes, int n_in,
                              void* d_out, int out_size, void* d_ws, size_t ws_size,
                              hipStream_t stream) {
    const float* m_z   = (const float*)d_in[0];   // (n,2)
    const float* y     = (const float*)d_in[1];   // (n,1)
    const float* delta = (const float*)d_in[2];   // (n,1)
    float* out = (float*)d_out;
    const int n = in_sizes[1];                    // 8192

    float2* P = (float2*)d_ws;                    // IB * n * 8 B = 4 MB

    const double h = 1.3 * pow((double)n, -0.2);
    const double kk = 1.1774100225154747;         // sqrt(2 ln 2)
    const float inv_hk = (float)(1.0 / (h * kk));
    const float c1 = (float)(0.3989422804014327 / ((double)n * h)); // INV_SQRT_2PI/(n*h)
    const float invn = 1.0f / (float)n;
    const int span = n / IB;                      // 128

    const int nblk = (n + TPB - 1) / TPB;         // 32
    dim3 grid(nblk, IB);                          // 2048 blocks = 8/CU
    pair_kernel<<<grid, TPB, 0, stream>>>(m_z, y, delta, P, out, inv_hk, n, span);
    finalize_kernel<<<nblk, TPB, 0, stream>>>(P, m_z, y, delta, out, c1, invn, n);
}

// Round 7
// 90.369 us; speedup vs baseline: 1.0967x; 1.0967x over previous
//
#include <hip/hip_runtime.h>
#include <math.h>

#define TPB 256
#define IB 64            // i-blocks; span = n/IB = 128
#define EPSF 1e-15f

// Fused prep + O(n^2) pair kernel (R4 LDS-broadcast structure).
// Rs = (g1+log y)/(h*sqrt(2 ln 2)) so exp(-0.5*((R_i-R_j)/h)^2) = exp2(-dr^2).
// A_j = sum_i d_i*e;  L*Phi = 0.5*L + copysign(L,dr)*(0.5-u),
// u = Q(|dr_true|) via A&S 7.1.25 3-term erfc, REUSING the same exp2.
// 0.5*sum_span(L) folded once (spans partition i, telescopes to 0.5*sum L).
// v_rcp replaced by int-magic seed + 2 Newton (rel err ~4e-5): tests the
// trans=16cyc hypothesis — trans pipe load halves (1 exp/pair only).
template <int SPAN>
__global__ __launch_bounds__(TPB, 8) void pair_kernel(
    const float* __restrict__ m_z, const float* __restrict__ y,
    const float* __restrict__ delta, float2* __restrict__ P,
    float* __restrict__ out, float inv_hk, int n, int span_rt) {
    const int span = SPAN ? SPAN : span_rt;
    __shared__ float sR[256], sD[256], sL[256];
    __shared__ float sLtot;
    const int tid = threadIdx.x;
    const int j = blockIdx.x * TPB + tid;
    const float2* __restrict__ mz2 = (const float2*)m_z;

    if (j == 0 && blockIdx.y == 0) out[0] = 0.0f;  // harness poisons d_out

    const float2 gj = mz2[j];
    const float Rj = (gj.x + __logf(y[j])) * inv_hk;

    // prep this block's i-span into LDS (span <= 256)
    const int ibase = blockIdx.y * span;
    if (tid < span) {
        const int i = ibase + tid;
        const float2 g = mz2[i];
        sR[tid] = (g.x + __logf(y[i])) * inv_hk;
        sD[tid] = delta[i];
        sL[tid] = __expf(g.y - g.x);
    }
    __syncthreads();
    if (tid < 64) {  // wave 0: sum L over the span
        float s = 0.0f;
        for (int t = tid; t < span; t += 64) s += sL[t];
        for (int o = 32; o > 0; o >>= 1) s += __shfl_down(s, o, 64);
        if (tid == 0) sLtot = s;
    }
    __syncthreads();

    const float4* __restrict__ sR4 = (const float4*)sR;
    const float4* __restrict__ sD4 = (const float4*)sD;
    const float4* __restrict__ sL4 = (const float4*)sL;

    float a0 = 0, a1 = 0, a2 = 0, a3 = 0;
    float b0 = 0.5f * sLtot, b1 = 0, b2 = 0, b3 = 0;
    const int m = span >> 2;
#pragma unroll 8
    for (int k = 0; k < m; ++k) {
        const float4 R4 = sR4[k];   // three b128 broadcast reads per 4 pairs
        const float4 D4 = sD4[k];
        const float4 L4 = sL4[k];
#define PAIR(p, ACC_A, ACC_B)                                                  \
    {                                                                          \
        const float dr = R4.p - Rj;                                            \
        const float q = dr * dr;                                               \
        const float e = __builtin_amdgcn_exp2f(-q); /* exp(-dr_true^2/2) */    \
        const float a = fmaf(0.3916993f, fabsf(dr), 1.0f);                     \
        float t = __int_as_float(0x7EF127EAu - __float_as_int(a));             \
        t = t * fmaf(-a, t, 2.0f);  /* Newton 1 */                             \
        t = t * fmaf(-a, t, 2.0f);  /* Newton 2: rel err ~4e-5 */              \
        const float u = t * fmaf(t, fmaf(t, 0.3739278f, -0.0479399f),          \
                                 0.1740121f) * e;                              \
        ACC_A = fmaf(D4.p, e, ACC_A);                                          \
        ACC_B = fmaf(copysignf(L4.p, dr), 0.5f - u, ACC_B);                    \
    }
        PAIR(x, a0, b0)
        PAIR(y, a1, b1)
        PAIR(z, a2, b2)
        PAIR(w, a3, b3)
#undef PAIR
    }
    P[(size_t)blockIdx.y * n + j] =
        make_float2((a0 + a1) + (a2 + a3), (b0 + b1) + (b2 + b3));
}

// out = (1/n) * sum_j d_j * (R_j - g2_j - log(c1*A_j + eps) + log(invn*B_j + eps))
__global__ __launch_bounds__(TPB) void finalize_kernel(
    const float2* __restrict__ P, const float* __restrict__ m_z,
    const float* __restrict__ y, const float* __restrict__ delta,
    float* __restrict__ out, float c1, float invn, int n) {
    const int j = blockIdx.x * TPB + threadIdx.x;
    float sa = 0.0f, sb = 0.0f;
    for (int b = 0; b < IB; ++b) {               // coalesced float2 reads
        const float2 v = P[(size_t)b * n + j];
        sa += v.x;
        sb += v.y;
    }
    const float d = delta[j];
    const float R = m_z[2 * j] + __logf(y[j]);
    float term = d * (R - m_z[2 * j + 1] - __logf(fmaf(c1, sa, EPSF))
                                         + __logf(fmaf(invn, sb, EPSF)));
    for (int o = 32; o > 0; o >>= 1) term += __shfl_down(term, o, 64);
    __shared__ float wsum[TPB / 64];
    if ((threadIdx.x & 63) == 0) wsum[threadIdx.x >> 6] = term;
    __syncthreads();
    if (threadIdx.x == 0) {
        float ssum = 0.0f;
        for (int w = 0; w < TPB / 64; ++w) ssum += wsum[w];
        atomicAdd(out, ssum * invn);
    }
}

extern "C" void kernel_launch(void* const* d_in, const int* in_sizes, int n_in,
                              void* d_out, int out_size, void* d_ws, size_t ws_size,
                              hipStream_t stream) {
    const float* m_z   = (const float*)d_in[0];   // (n,2)
    const float* y     = (const float*)d_in[1];   // (n,1)
    const float* delta = (const float*)d_in[2];   // (n,1)
    float* out = (float*)d_out;
    const int n = in_sizes[1];                    // 8192

    float2* P = (float2*)d_ws;                    // IB * n * 8 B = 4 MB

    const double h = 1.3 * pow((double)n, -0.2);
    const double kk = 1.1774100225154747;         // sqrt(2 ln 2)
    const float inv_hk = (float)(1.0 / (h * kk));
    const float c1 = (float)(0.3989422804014327 / ((double)n * h)); // INV_SQRT_2PI/(n*h)
    const float invn = 1.0f / (float)n;
    const int span = n / IB;                      // 128

    const int nblk = (n + TPB - 1) / TPB;         // 32
    dim3 grid(nblk, IB);                          // 2048 blocks = 8/CU
    if (span == 128)
        pair_kernel<128><<<grid, TPB, 0, stream>>>(m_z, y, delta, P, out,
                                                   inv_hk, n, span);
    else
        pair_kernel<0><<<grid, TPB, 0, stream>>>(m_z, y, delta, P, out,
                                                 inv_hk, n, span);
    finalize_kernel<<<nblk, TPB, 0, stream>>>(P, m_z, y, delta, out, c1, invn, n);
}

// Round 8
// 88.510 us; speedup vs baseline: 1.1197x; 1.0210x over previous
//
#include <hip/hip_runtime.h>
#include <math.h>

#define TPB 256
#define IB 64            // i-blocks; span = n/IB = 128
#define EPSF 1e-15f

// Fused prep + O(n^2) pair kernel (R4 structure, 2-plane LDS packing).
// LDS holds {R_i, V_i} float2, V = d_i ? -L_i : +L_i (sign bit carries d;
// L = exp(g2-g1) > 0). Inner loop reads ONE ds_read_b128 per 2 pairs —
// 24 LDS-pipe cyc per 4 pairs vs R4's 40 (LDS/VALU were co-limited).
// Rs = (g1+log y)/(h*sqrt(2 ln 2)) so exp(-0.5*((R_i-R_j)/h)^2) = exp2(-dr^2).
// A_j = sum_{d_i=1} e = 0.5*(sum e - sum copysign(e, V_i))      [sign trick]
// B_j = 0.5*sum_span(L) + sum copysign(L_i, dr)*(0.5 - u)       [as R4]
// u = Q(|dr_true|) via A&S 7.1.25 3-term erfc, REUSING the same exp2.
template <int SPAN>
__global__ __launch_bounds__(TPB, 8) void pair_kernel(
    const float* __restrict__ m_z, const float* __restrict__ y,
    const float* __restrict__ delta, float2* __restrict__ P,
    float* __restrict__ out, float inv_hk, int n, int span_rt) {
    const int span = SPAN ? SPAN : span_rt;
    __shared__ float2 sRV[256];
    __shared__ float sLtot;
    const int tid = threadIdx.x;
    const int j = blockIdx.x * TPB + tid;
    const float2* __restrict__ mz2 = (const float2*)m_z;

    if (j == 0 && blockIdx.y == 0) out[0] = 0.0f;  // harness poisons d_out

    const float2 gj = mz2[j];
    const float Rj = (gj.x + __logf(y[j])) * inv_hk;

    // prep this block's i-span into LDS (span <= 256)
    const int ibase = blockIdx.y * span;
    if (tid < span) {
        const int i = ibase + tid;
        const float2 g = mz2[i];
        const float L = __expf(g.y - g.x);
        sRV[tid] = make_float2((g.x + __logf(y[i])) * inv_hk,
                               (delta[i] != 0.0f) ? -L : L);
    }
    __syncthreads();
    if (tid < 64) {  // wave 0: sum L over the span
        float s = 0.0f;
        for (int t = tid; t < span; t += 64) s += fabsf(sRV[t].y);
        for (int o = 32; o > 0; o >>= 1) s += __shfl_down(s, o, 64);
        if (tid == 0) sLtot = s;
    }
    __syncthreads();

    const float4* __restrict__ s4 = (const float4*)sRV;  // {R0,V0,R1,V1}

    float e0 = 0, e1 = 0, e2 = 0, e3 = 0;      // sum e
    float s0 = 0, s1 = 0, s2 = 0, s3 = 0;      // sum copysign(e, V)
    float b0 = 0.5f * sLtot, b1 = 0, b2 = 0, b3 = 0;
    const int m = span >> 2;
#pragma unroll 4
    for (int k = 0; k < m; ++k) {
        const float4 p0 = s4[2 * k];       // pairs 4k, 4k+1
        const float4 p1 = s4[2 * k + 1];   // pairs 4k+2, 4k+3
#define PAIR(RR, VV, ACC_E, ACC_S, ACC_B)                                      \
    {                                                                          \
        const float dr = RR - Rj;                                              \
        const float e = __builtin_amdgcn_exp2f(-(dr * dr));                    \
        const float a = fmaf(0.3916993f, fabsf(dr), 1.0f);                     \
        const float t = __builtin_amdgcn_rcpf(a);                              \
        const float u = t * fmaf(t, fmaf(t, 0.3739278f, -0.0479399f),          \
                                 0.1740121f) * e;                              \
        ACC_E += e;                                                            \
        ACC_S += copysignf(e, VV);              /* v_bfi */                    \
        ACC_B = fmaf(copysignf(fabsf(VV), dr),  /* v_bfi */                    \
                     0.5f - u, ACC_B);                                         \
    }
        PAIR(p0.x, p0.y, e0, s0, b0)
        PAIR(p0.z, p0.w, e1, s1, b1)
        PAIR(p1.x, p1.y, e2, s2, b2)
        PAIR(p1.z, p1.w, e3, s3, b3)
#undef PAIR
    }
    const float sumE = (e0 + e1) + (e2 + e3);
    const float sumS = (s0 + s1) + (s2 + s3);
    P[(size_t)blockIdx.y * n + j] =
        make_float2(0.5f * (sumE - sumS), (b0 + b1) + (b2 + b3));
}

// out = (1/n) * sum_j d_j * (R_j - g2_j - log(c1*A_j + eps) + log(invn*B_j + eps))
__global__ __launch_bounds__(TPB) void finalize_kernel(
    const float2* __restrict__ P, const float* __restrict__ m_z,
    const float* __restrict__ y, const float* __restrict__ delta,
    float* __restrict__ out, float c1, float invn, int n) {
    const int j = blockIdx.x * TPB + threadIdx.x;
    float sa = 0.0f, sb = 0.0f;
    for (int b = 0; b < IB; ++b) {               // coalesced float2 reads
        const float2 v = P[(size_t)b * n + j];
        sa += v.x;
        sb += v.y;
    }
    const float d = delta[j];
    const float R = m_z[2 * j] + __logf(y[j]);
    float term = d * (R - m_z[2 * j + 1] - __logf(fmaf(c1, sa, EPSF))
                                         + __logf(fmaf(invn, sb, EPSF)));
    for (int o = 32; o > 0; o >>= 1) term += __shfl_down(term, o, 64);
    __shared__ float wsum[TPB / 64];
    if ((threadIdx.x & 63) == 0) wsum[threadIdx.x >> 6] = term;
    __syncthreads();
    if (threadIdx.x == 0) {
        float ssum = 0.0f;
        for (int w = 0; w < TPB / 64; ++w) ssum += wsum[w];
        atomicAdd(out, ssum * invn);
    }
}

extern "C" void kernel_launch(void* const* d_in, const int* in_sizes, int n_in,
                              void* d_out, int out_size, void* d_ws, size_t ws_size,
                              hipStream_t stream) {
    const float* m_z   = (const float*)d_in[0];   // (n,2)
    const float* y     = (const float*)d_in[1];   // (n,1)
    const float* delta = (const float*)d_in[2];   // (n,1)
    float* out = (float*)d_out;
    const int n = in_sizes[1];                    // 8192

    float2* P = (float2*)d_ws;                    // IB * n * 8 B = 4 MB

    const double h = 1.3 * pow((double)n, -0.2);
    const double kk = 1.1774100225154747;         // sqrt(2 ln 2)
    const float inv_hk = (float)(1.0 / (h * kk));
    const float c1 = (float)(0.3989422804014327 / ((double)n * h)); // INV_SQRT_2PI/(n*h)
    const float invn = 1.0f / (float)n;
    const int span = n / IB;                      // 128

    const int nblk = (n + TPB - 1) / TPB;         // 32
    dim3 grid(nblk, IB);                          // 2048 blocks = 8/CU
    if (span == 128)
        pair_kernel<128><<<grid, TPB, 0, stream>>>(m_z, y, delta, P, out,
                                                   inv_hk, n, span);
    else
        pair_kernel<0><<<grid, TPB, 0, stream>>>(m_z, y, delta, P, out,
                                                 inv_hk, n, span);
    finalize_kernel<<<nblk, TPB, 0, stream>>>(P, m_z, y, delta, out, c1, invn, n);
}

// Round 9
// 82.684 us; speedup vs baseline: 1.1986x; 1.0705x over previous
//
#include <hip/hip_runtime.h>
#include <math.h>

#define TPB 256
#define IB 64
#define EPSF 1e-15f

// R4 structure verbatim; ONLY change: v_rcp -> magic seed + 1 Newton step.
// Tests the trans=16cyc/wave64 hypothesis with no confounds (R7 changed
// layout+unroll simultaneously and regressed; this is the minimal diff).
// Rs = (g1+log y)/(h*sqrt(2 ln 2)) so exp(-0.5*((R_i-R_j)/h)^2) = exp2(-dr^2).
// A_j = sum_i d_i*e;  L*Phi = 0.5*L + copysign(L,dr)*(0.5-u),
// u = Q via A&S 7.1.25 3-term erfc (|eps|<=2.5e-5), reusing the SAME exp2.
// 0.5*sum_span(L) folded once (spans partition i, telescopes to 0.5*sum L).
__global__ __launch_bounds__(TPB, 8) void pair_kernel(
    const float* __restrict__ m_z, const float* __restrict__ y,
    const float* __restrict__ delta, float2* __restrict__ P,
    float* __restrict__ out, float inv_hk, int n, int span) {
    __shared__ float4 sRd[128];   // {R_2k, R_2k+1, d_2k, d_2k+1}
    __shared__ float2 sL2[128];   // {L_2k, L_2k+1}
    __shared__ float sLtot;
    const int tid = threadIdx.x;
    const int j = blockIdx.x * TPB + tid;
    const float2* __restrict__ mz2 = (const float2*)m_z;

    if (j == 0 && blockIdx.y == 0) out[0] = 0.0f;  // harness poisons d_out

    const float2 gj = mz2[j];
    const float Rj = (gj.x + __logf(y[j])) * inv_hk;

    // prep this block's i-span into LDS (span <= 256)
    const int ibase = blockIdx.y * span;
    if (tid < span) {
        const int i = ibase + tid;
        const float2 g = mz2[i];
        float* s = (float*)sRd;
        const int pk = tid >> 1, hf = tid & 1;
        s[4 * pk + hf]     = (g.x + __logf(y[i])) * inv_hk;
        s[4 * pk + 2 + hf] = delta[i];
        ((float*)sL2)[tid] = __expf(g.y - g.x);
    }
    __syncthreads();
    if (tid < 64) {  // wave 0: sum L over the span
        float s = 0.0f;
        for (int t = tid; t < span; t += 64) s += ((float*)sL2)[t];
        for (int o = 32; o > 0; o >>= 1) s += __shfl_down(s, o, 64);
        if (tid == 0) sLtot = s;
    }
    __syncthreads();

    float a0 = 0.0f, a1 = 0.0f, b0 = 0.5f * sLtot, b1 = 0.0f;
    const int m = span >> 1;
#pragma unroll 4
    for (int k = 0; k < m; ++k) {
        const float4 rd = sRd[k];                 // broadcast LDS reads
        const float2 ll = sL2[k];
        const float dr0 = rd.x - Rj;
        const float dr1 = rd.y - Rj;
        const float e0 = __builtin_amdgcn_exp2f(-(dr0 * dr0));  // exp(-drt^2/2)
        const float e1 = __builtin_amdgcn_exp2f(-(dr1 * dr1));
        const float A0 = fmaf(0.3916993f, fabsf(dr0), 1.0f);
        const float A1 = fmaf(0.3916993f, fabsf(dr1), 1.0f);
        // rcp via int-magic seed + ONE Newton step (rel err ~2.5e-3):
        // removes one trans op per pair; +3 cheap VALU.
        float t0 = __int_as_float(0x7EF127EAu - __float_as_int(A0));
        float t1 = __int_as_float(0x7EF127EAu - __float_as_int(A1));
        t0 = t0 * fmaf(-A0, t0, 2.0f);
        t1 = t1 * fmaf(-A1, t1, 2.0f);
        const float u0 = t0 * fmaf(t0, fmaf(t0, 0.3739278f, -0.0479399f), 0.1740121f) * e0;
        const float u1 = t1 * fmaf(t1, fmaf(t1, 0.3739278f, -0.0479399f), 0.1740121f) * e1;
        a0 = fmaf(rd.z, e0, a0);
        a1 = fmaf(rd.w, e1, a1);
        b0 = fmaf(copysignf(ll.x, dr0), 0.5f - u0, b0);
        b1 = fmaf(copysignf(ll.y, dr1), 0.5f - u1, b1);
    }
    P[(size_t)blockIdx.y * n + j] = make_float2(a0 + a1, b0 + b1);
}

// out = (1/n) * sum_j d_j * (R_j - g2_j - log(c1*A_j + eps) + log(invn*B_j + eps))
__global__ __launch_bounds__(TPB) void finalize_kernel(
    const float2* __restrict__ P, const float* __restrict__ m_z,
    const float* __restrict__ y, const float* __restrict__ delta,
    float* __restrict__ out, float c1, float invn, int n) {
    const int j = blockIdx.x * TPB + threadIdx.x;
    float sa = 0.0f, sb = 0.0f;
    for (int b = 0; b < IB; ++b) {               // coalesced float2 reads
        const float2 v = P[(size_t)b * n + j];
        sa += v.x;
        sb += v.y;
    }
    const float d = delta[j];
    const float R = m_z[2 * j] + __logf(y[j]);
    float term = d * (R - m_z[2 * j + 1] - __logf(fmaf(c1, sa, EPSF))
                                         + __logf(fmaf(invn, sb, EPSF)));
    for (int o = 32; o > 0; o >>= 1) term += __shfl_down(term, o, 64);
    __shared__ float wsum[TPB / 64];
    if ((threadIdx.x & 63) == 0) wsum[threadIdx.x >> 6] = term;
    __syncthreads();
    if (threadIdx.x == 0) {
        float ssum = 0.0f;
        for (int w = 0; w < TPB / 64; ++w) ssum += wsum[w];
        atomicAdd(out, ssum * invn);
    }
}

extern "C" void kernel_launch(void* const* d_in, const int* in_sizes, int n_in,
                              void* d_out, int out_size, void* d_ws, size_t ws_size,
                              hipStream_t stream) {
    const float* m_z   = (const float*)d_in[0];   // (n,2)
    const float* y     = (const float*)d_in[1];   // (n,1)
    const float* delta = (const float*)d_in[2];   // (n,1)
    float* out = (float*)d_out;
    const int n = in_sizes[1];                    // 8192

    float2* P = (float2*)d_ws;                    // IB * n * 8 B = 4 MB

    const double h = 1.3 * pow((double)n, -0.2);
    const double kk = 1.1774100225154747;         // sqrt(2 ln 2)
    const float inv_hk = (float)(1.0 / (h * kk));
    const float c1 = (float)(0.3989422804014327 / ((double)n * h)); // INV_SQRT_2PI/(n*h)
    const float invn = 1.0f / (float)n;
    const int span = n / IB;                      // 128

    const int nblk = (n + TPB - 1) / TPB;         // 32
    dim3 grid(nblk, IB);                          // 2048 blocks = 8/CU
    pair_kernel<<<grid, TPB, 0, stream>>>(m_z, y, delta, P, out, inv_hk, n, span);
    finalize_kernel<<<nblk, TPB, 0, stream>>>(P, m_z, y, delta, out, c1, invn, n);
}